// Round 14
// baseline (507.354 us; speedup 1.0000x reference)
//
#include <hip/hip_runtime.h>

#define NN 50000
#define NE 800000
#define NG 256
#define DD 256
#define NL 3
#define BN_EPS 1e-5f
#define MPAD 50048   // 782 * 64
#define CAP 96       // per-node edge bucket capacity
#define MB2 782      // MPAD / 64 (m-blocks for fused agg+MLP)
#define NBIN 196     // ceil(NN/256) dst bins
#define BINCAP 4608  // fixed binbuf window per bin (mean 4082, +8 sigma)

typedef short bf16x8 __attribute__((ext_vector_type(8)));
typedef float f32x4 __attribute__((ext_vector_type(4)));
typedef unsigned short ushort8 __attribute__((ext_vector_type(8)));

__device__ __forceinline__ unsigned short f2bf(float f) {
    unsigned int u = __float_as_uint(f);
    u += 0x7FFFu + ((u >> 16) & 1u);
    return (unsigned short)(u >> 16);
}
__device__ __forceinline__ float bf2f(unsigned short s) {
    return __uint_as_float(((unsigned int)s) << 16);
}

// ---------- fused setup: f2bf(x), wconv, zrow, gbounds, bin_cnt=0 ----------
#define R0 3200000          // f2bf float4 groups (NN*DD/4)
#define R1 393216           // wconv elems (6*65536)
#define R2 256              // zrow (sentinel row)
#define R3 256              // gbounds
#define R4 NBIN             // bin_cnt zero
#define RTOT (R0 + R1 + R2 + R3 + R4)

__global__ void k_setup(const float* __restrict__ x, const float* __restrict__ w1,
                        const float* __restrict__ w2, const int* __restrict__ batch,
                        unsigned short* __restrict__ hbf, unsigned short* __restrict__ wt,
                        int* __restrict__ gstart, int* __restrict__ bin_cnt) {
    int i = blockIdx.x * blockDim.x + threadIdx.x;
    if (i < R0) {
        float4 v = ((const float4*)x)[i];
        ushort4 o;
        o.x = f2bf(v.x); o.y = f2bf(v.y); o.z = f2bf(v.z); o.w = f2bf(v.w);
        ((ushort4*)hbf)[i] = o;
        return;
    }
    i -= R0;
    if (i < R1) {
        int mat = i >> 16;
        int n = (i >> 8) & 255;
        int k = i & 255;
        const float* src = (mat < 3) ? (w1 + ((size_t)mat << 16)) : (w2 + ((size_t)(mat - 3) << 16));
        wt[i] = f2bf(src[k * 256 + n]);
        return;
    }
    i -= R1;
    if (i < R2) { hbf[(size_t)NN * DD + i] = 0; return; }
    i -= R2;
    if (i < R3) {
        int g = i;
        int lo = 0, hi = NN;
        while (lo < hi) {
            int mid = (lo + hi) >> 1;
            if (batch[mid] < g) lo = mid + 1; else hi = mid;
        }
        gstart[g] = lo;
        if (g == 0) gstart[NG] = NN;
        return;
    }
    i -= R3;
    if (i < R4) bin_cnt[i] = 0;
}

// ---------- binned CSR build, 2 kernels (fixed per-bin windows) ----------
__global__ __launch_bounds__(256) void k_bin2(const int* __restrict__ ei,
                                              int* __restrict__ bin_cnt,
                                              unsigned int* __restrict__ binbuf) {
    __shared__ int hist[NBIN], base[NBIN], lcur[NBIN];
    int t = threadIdx.x;
    for (int i = t; i < NBIN; i += 256) { hist[i] = 0; lcur[i] = 0; }
    __syncthreads();
    int d[4], s[4];
    #pragma unroll
    for (int j = 0; j < 4; ++j) {
        int e = blockIdx.x * 1024 + j * 256 + t;
        if (e < NE) {
            s[j] = ei[e];
            d[j] = ei[NE + e];
            atomicAdd(&hist[d[j] >> 8], 1);
        } else d[j] = -1;
    }
    __syncthreads();
    for (int i = t; i < NBIN; i += 256)
        base[i] = hist[i] ? atomicAdd(&bin_cnt[i], hist[i]) : 0;
    __syncthreads();
    #pragma unroll
    for (int j = 0; j < 4; ++j) {
        if (d[j] >= 0) {
            int b = d[j] >> 8;
            int o = atomicAdd(&lcur[b], 1);
            binbuf[(size_t)b * BINCAP + base[b] + o] = (unsigned)s[j] | ((unsigned)(d[j] & 255) << 16);
        }
    }
}

__global__ __launch_bounds__(256) void k_bin3(const unsigned int* __restrict__ binbuf,
                                              const int* __restrict__ bin_cnt,
                                              unsigned short* __restrict__ elist,
                                              int* __restrict__ deg) {
    __shared__ int ldeg[256];
    int b = blockIdx.x, t = threadIdx.x;
    ldeg[t] = 0;
    __syncthreads();
    int cnt = bin_cnt[b];
    const unsigned int* bb = binbuf + (size_t)b * BINCAP;
    for (int i = t; i < cnt; i += 256) {
        unsigned v = bb[i];
        int src = v & 0xFFFF;
        int dl = v >> 16;
        int pos = atomicAdd(&ldeg[dl], 1);
        elist[(size_t)(b * 256 + dl) * CAP + pos] = (unsigned short)src;
    }
    __syncthreads();
    int node = b * 256 + t;
    if (node < NN) deg[node] = ldeg[t];
}

// ---------- fused agg + MLP: z = h+sum(h[src]) -> relu(relu(z@W1+b1)@W2+b2) ----------
// Block owns 64 rows. Phase A gathers z into LDS (ZH, H1-swizzled). ZH is reused
// for h1 after GEMM1 (z dead then). LDS 66KB -> 2 blocks/CU; one block's gather
// overlaps the other's MFMA.
__global__ __launch_bounds__(256, 2) void k_mlp(const unsigned short* __restrict__ hbf,
                                                const int* __restrict__ deg,
                                                const unsigned short* __restrict__ elist,
                                                const unsigned short* __restrict__ BT1,
                                                const unsigned short* __restrict__ BT2,
                                                const float* __restrict__ b1,
                                                const float* __restrict__ b2,
                                                unsigned short* __restrict__ Cout,
                                                float* __restrict__ pstat) {
    __shared__ short ZH[64 * 256];     // z (phase A/B) then h1 (phase C), group-swizzled (32 KB)
    __shared__ short Bs[256 * 64];     // W1T / W2T k-chunk (32 KB, reused)
    __shared__ float spart[256][2];    // per-col sum/sumsq (2 KB)
    int tid = threadIdx.x;
    int lane = tid & 63;
    int wv = tid >> 6;                 // wave id; also output col quadrant
    long m0 = (long)blockIdx.x * 64;
    const int r = lane & 15, hi = lane >> 4;

    // ---- Phase A: aggregate this block's 64 z-rows into ZH ----
    {
        int chunk = lane & 31;         // 16B chunk within 512B row
        int half = lane >> 5;          // 0: own+even edges, 1: odd edges
        const ushort8* h8 = (const ushort8*)hbf;
        for (int p = 0; p < 16; ++p) {
            int row = wv * 16 + p;
            long node = m0 + row;
            if (node < NN) {
                float acc8[8];
                if (half == 0) {
                    ushort8 own = h8[(size_t)node * 32 + chunk];
                    #pragma unroll
                    for (int j = 0; j < 8; ++j) acc8[j] = bf2f(own[j]);
                } else {
                    #pragma unroll
                    for (int j = 0; j < 8; ++j) acc8[j] = 0.f;
                }
                int n = deg[node];
                const unsigned short* el = elist + (size_t)node * CAP;
                int i = 0;
                for (; i + 8 <= n; i += 8) {
                    ushort8 sv = *(const ushort8*)(el + i);
                    int i0 = half ? sv[1] : sv[0];
                    int i1 = half ? sv[3] : sv[2];
                    int i2 = half ? sv[5] : sv[4];
                    int i3 = half ? sv[7] : sv[6];
                    ushort8 r0 = h8[(size_t)i0 * 32 + chunk];
                    ushort8 r1 = h8[(size_t)i1 * 32 + chunk];
                    ushort8 r2 = h8[(size_t)i2 * 32 + chunk];
                    ushort8 r3 = h8[(size_t)i3 * 32 + chunk];
                    #pragma unroll
                    for (int j = 0; j < 8; ++j) acc8[j] += bf2f(r0[j]);
                    #pragma unroll
                    for (int j = 0; j < 8; ++j) acc8[j] += bf2f(r1[j]);
                    #pragma unroll
                    for (int j = 0; j < 8; ++j) acc8[j] += bf2f(r2[j]);
                    #pragma unroll
                    for (int j = 0; j < 8; ++j) acc8[j] += bf2f(r3[j]);
                }
                for (; i < n; i += 2) {
                    int s0 = el[i];
                    int s1 = (i + 1 < n) ? (int)el[i + 1] : NN;   // sentinel zero row
                    int idx = half ? s1 : s0;
                    ushort8 rr = h8[(size_t)idx * 32 + chunk];
                    #pragma unroll
                    for (int j = 0; j < 8; ++j) acc8[j] += bf2f(rr[j]);
                }
                ushort8 o;
                #pragma unroll
                for (int j = 0; j < 8; ++j) {
                    float other = __shfl_xor(acc8[j], 32);
                    o[j] = f2bf(acc8[j] + other);
                }
                if (half == 0)
                    *(ushort8*)(ZH + row * 256 + ((chunk ^ (row & 7))) * 8) = o;
            } else {
                if (half == 0) {
                    ushort8 o = (ushort8){0,0,0,0,0,0,0,0};
                    *(ushort8*)(ZH + row * 256 + ((chunk ^ (row & 7))) * 8) = o;
                }
            }
        }
    }

    f32x4 acc[4][4];
    #pragma unroll
    for (int m = 0; m < 4; ++m)
        #pragma unroll
        for (int n = 0; n < 4; ++n)
            acc[m][n] = (f32x4){0.f, 0.f, 0.f, 0.f};

    // ---- Phase B (GEMM1): h1 = relu(z @ W1 + b1), A from ZH ----
    for (int k0 = 0; k0 < DD; k0 += 64) {
        #pragma unroll
        for (int p = 0; p < 8; ++p) {
            int flat = p * 256 + tid;
            int row = flat >> 3, c8 = flat & 7;
            int slot = c8 ^ (row & 7);
            *(bf16x8*)(Bs + row * 64 + slot * 8) =
                *(const bf16x8*)(BT1 + (long)row * DD + k0 + c8 * 8);
        }
        __syncthreads();   // also covers phase-A ZH writes on first iteration
        bf16x8 af[4][2], bfr[4][2];
        #pragma unroll
        for (int m = 0; m < 4; ++m) {
            int row = m * 16 + r;
            #pragma unroll
            for (int kk = 0; kk < 2; ++kk) {
                int g = (k0 >> 3) + kk * 4 + hi;
                af[m][kk] = *(const bf16x8*)(ZH + row * 256 + (g ^ (row & 7)) * 8);
            }
        }
        #pragma unroll
        for (int n = 0; n < 4; ++n) {
            int col = wv * 64 + n * 16 + r;
            #pragma unroll
            for (int kk = 0; kk < 2; ++kk) {
                int slot = (kk * 4 + hi) ^ (col & 7);
                bfr[n][kk] = *(const bf16x8*)(Bs + col * 64 + slot * 8);
            }
        }
        #pragma unroll
        for (int kk = 0; kk < 2; ++kk)
            #pragma unroll
            for (int m = 0; m < 4; ++m)
                #pragma unroll
                for (int n = 0; n < 4; ++n)
                    acc[m][n] = __builtin_amdgcn_mfma_f32_16x16x32_bf16(af[m][kk], bfr[n][kk], acc[m][n], 0, 0, 0);
        __syncthreads();
    }

    // h1 epilogue -> ZH (z is dead; same group-swizzled layout)
    #pragma unroll
    for (int n = 0; n < 4; ++n) {
        int col = wv * 64 + n * 16 + r;
        float bv = b1[col];
        int g = col >> 3, j8 = col & 7;
        #pragma unroll
        for (int m = 0; m < 4; ++m) {
            #pragma unroll
            for (int j = 0; j < 4; ++j) {
                int row = m * 16 + hi * 4 + j;
                float v = acc[m][n][j] + bv;
                v = v > 0.f ? v : 0.f;
                ZH[row * 256 + (g ^ (row & 7)) * 8 + j8] = (short)f2bf(v);
            }
        }
    }
    #pragma unroll
    for (int m = 0; m < 4; ++m)
        #pragma unroll
        for (int n = 0; n < 4; ++n)
            acc[m][n] = (f32x4){0.f, 0.f, 0.f, 0.f};
    __syncthreads();

    // ---- Phase C (GEMM2): y = relu(h1 @ W2 + b2) ----
    for (int k0 = 0; k0 < DD; k0 += 64) {
        #pragma unroll
        for (int p = 0; p < 8; ++p) {
            int flat = p * 256 + tid;
            int row = flat >> 3, c8 = flat & 7;
            int slot = c8 ^ (row & 7);
            *(bf16x8*)(Bs + row * 64 + slot * 8) =
                *(const bf16x8*)(BT2 + (long)row * DD + k0 + c8 * 8);
        }
        __syncthreads();
        bf16x8 af[4][2], bfr[4][2];
        #pragma unroll
        for (int m = 0; m < 4; ++m) {
            int row = m * 16 + r;
            #pragma unroll
            for (int kk = 0; kk < 2; ++kk) {
                int g = (k0 >> 3) + kk * 4 + hi;
                af[m][kk] = *(const bf16x8*)(ZH + row * 256 + (g ^ (row & 7)) * 8);
            }
        }
        #pragma unroll
        for (int n = 0; n < 4; ++n) {
            int col = wv * 64 + n * 16 + r;
            #pragma unroll
            for (int kk = 0; kk < 2; ++kk) {
                int slot = (kk * 4 + hi) ^ (col & 7);
                bfr[n][kk] = *(const bf16x8*)(Bs + col * 64 + slot * 8);
            }
        }
        #pragma unroll
        for (int kk = 0; kk < 2; ++kk)
            #pragma unroll
            for (int m = 0; m < 4; ++m)
                #pragma unroll
                for (int n = 0; n < 4; ++n)
                    acc[m][n] = __builtin_amdgcn_mfma_f32_16x16x32_bf16(af[m][kk], bfr[n][kk], acc[m][n], 0, 0, 0);
        __syncthreads();
    }

    // epilogue: bias + relu -> bf16 z out; BN partials from EXACT fp32 values
    #pragma unroll
    for (int n = 0; n < 4; ++n) {
        int col = wv * 64 + n * 16 + r;
        float bv = b2[col];
        float cs = 0.f, cs2 = 0.f;
        #pragma unroll
        for (int m = 0; m < 4; ++m) {
            #pragma unroll
            for (int j = 0; j < 4; ++j) {
                long grow = m0 + m * 16 + hi * 4 + j;
                float v = acc[m][n][j] + bv;
                v = v > 0.f ? v : 0.f;
                Cout[grow * DD + col] = f2bf(v);
                float vm = (grow < NN) ? v : 0.f;
                cs += vm; cs2 += vm * vm;
            }
        }
        cs  += __shfl_xor(cs, 16);  cs  += __shfl_xor(cs, 32);
        cs2 += __shfl_xor(cs2, 16); cs2 += __shfl_xor(cs2, 32);
        if (hi == 0) {
            spart[col][0] = cs;
            spart[col][1] = cs2;
        }
    }
    __syncthreads();
    pstat[(size_t)blockIdx.x * 512 + tid] = spart[tid][0];
    pstat[(size_t)blockIdx.x * 512 + 256 + tid] = spart[tid][1];
}

// reduce per-block partials -> BN scale/shift (one block per column, fixed tree)
__global__ __launch_bounds__(256) void k_bnscale2(const float* __restrict__ pstat,
                                                  const float* __restrict__ gamma,
                                                  const float* __restrict__ beta,
                                                  float* __restrict__ ss) {
    int c = blockIdx.x;
    int t = threadIdx.x;
    float s = 0.f, s2 = 0.f;
    for (int mb = t; mb < MB2; mb += 256) {
        s  += pstat[(size_t)mb * 512 + c];
        s2 += pstat[(size_t)mb * 512 + 256 + c];
    }
    __shared__ float rs[256], rs2[256];
    rs[t] = s; rs2[t] = s2;
    __syncthreads();
    #pragma unroll
    for (int d = 128; d > 0; d >>= 1) {
        if (t < d) { rs[t] += rs[t + d]; rs2[t] += rs2[t + d]; }
        __syncthreads();
    }
    if (t == 0) {
        float mean = rs[0] * (1.0f / NN);
        float var = rs2[0] * (1.0f / NN) - mean * mean;
        float sc = gamma[c] * rsqrtf(var + BN_EPS);
        ss[c] = sc;
        ss[DD + c] = beta[c] - mean * sc;
    }
}

// fused BN-apply + bf16 emit + pool over bf16 z; grid (NG, 2): col-half per blockIdx.y.
template<int LAST>
__global__ __launch_bounds__(512) void k_bnpool(const unsigned short* __restrict__ z,
                                                const float* __restrict__ ss,
                                                const int* __restrict__ gstart,
                                                unsigned short* __restrict__ hbf,
                                                float* __restrict__ out, int layer) {
    __shared__ float4 red[16][32];
    int g = blockIdx.x;
    int ch = blockIdx.y;
    int t = threadIdx.x;
    int q = t & 31, rg = t >> 5;
    int cq = ch * 32 + q;
    float4 sc = ((const float4*)ss)[cq];
    float4 sh = ((const float4*)(ss + DD))[cq];
    int lo = gstart[g], hi = gstart[g + 1];
    float4 s = {0.f, 0.f, 0.f, 0.f};
    const ushort4* z4 = (const ushort4*)z;
    ushort4* h4 = (ushort4*)hbf;
    for (int r = lo + rg; r < hi; r += 16) {
        ushort4 zv = z4[(size_t)r * 64 + cq];
        float4 v;
        v.x = bf2f(zv.x) * sc.x + sh.x;
        v.y = bf2f(zv.y) * sc.y + sh.y;
        v.z = bf2f(zv.z) * sc.z + sh.z;
        v.w = bf2f(zv.w) * sc.w + sh.w;
        s.x += v.x; s.y += v.y; s.z += v.z; s.w += v.w;
        if (!LAST) {
            ushort4 o;
            o.x = f2bf(v.x); o.y = f2bf(v.y); o.z = f2bf(v.z); o.w = f2bf(v.w);
            h4[(size_t)r * 64 + cq] = o;
        }
    }
    red[rg][q] = s;
    __syncthreads();
    #pragma unroll
    for (int d = 8; d > 0; d >>= 1) {
        if (rg < d) {
            float4 a = red[rg][q], b = red[rg + d][q];
            a.x += b.x; a.y += b.y; a.z += b.z; a.w += b.w;
            red[rg][q] = a;
        }
        __syncthreads();
    }
    if (rg == 0) {
        ((float4*)(out + (size_t)g * (NL * DD) + layer * DD))[cq] = red[0][q];
    }
}

extern "C" void kernel_launch(void* const* d_in, const int* in_sizes, int n_in,
                              void* d_out, int out_size, void* d_ws, size_t ws_size,
                              hipStream_t stream) {
    const float* x     = (const float*)d_in[0];
    const int*   ei    = (const int*)d_in[1];
    const int*   batch = (const int*)d_in[2];
    const float* w1    = (const float*)d_in[3];
    const float* b1    = (const float*)d_in[4];
    const float* w2    = (const float*)d_in[5];
    const float* b2    = (const float*)d_in[6];
    const float* gamma = (const float*)d_in[7];
    const float* beta  = (const float*)d_in[8];
    float* out = (float*)d_out;

    char* ws = (char*)d_ws;
    size_t off = 0;
    auto alloc = [&](size_t bytes) -> void* {
        void* p = ws + off;
        off += (bytes + 255) & ~size_t(255);
        return p;
    };
    unsigned short* zB   = (unsigned short*)alloc((size_t)MPAD * DD * 2);        // bf16 MLP out
    unsigned short* hbf  = (unsigned short*)alloc((size_t)(NN + 64) * DD * 2);   // h bf16 + sentinel
    unsigned short* wt   = (unsigned short*)alloc((size_t)6 * DD * DD * 2);
    int* deg    = (int*)alloc((size_t)NN * 4);
    unsigned short* elist = (unsigned short*)alloc((size_t)NN * CAP * 2);
    unsigned int* binbuf = (unsigned int*)alloc((size_t)NBIN * BINCAP * 4);
    int* bin_cnt    = (int*)alloc(NBIN * 4);
    int* gstart = (int*)alloc((size_t)(NG + 1) * 4);
    float* pstat = (float*)alloc((size_t)MB2 * 512 * 4);
    float* ss   = (float*)alloc(2 * DD * 4);

    k_setup<<<(RTOT + 255) / 256, 256, 0, stream>>>(x, w1, w2, batch, hbf, wt, gstart, bin_cnt);
    const int EB = (NE + 1023) / 1024;   // 782
    k_bin2<<<EB, 256, 0, stream>>>(ei, bin_cnt, binbuf);
    k_bin3<<<NBIN, 256, 0, stream>>>(binbuf, bin_cnt, elist, deg);

    for (int l = 0; l < NL; ++l) {
        k_mlp<<<MB2, 256, 0, stream>>>(hbf, deg, elist,
                                       wt + (size_t)l * DD * DD,
                                       wt + (size_t)(3 + l) * DD * DD,
                                       b1 + l * DD, b2 + l * DD, zB, pstat);
        k_bnscale2<<<DD, 256, 0, stream>>>(pstat, gamma + l * DD, beta + l * DD, ss);
        if (l < NL - 1)
            k_bnpool<0><<<dim3(NG, 2), 512, 0, stream>>>(zB, ss, gstart, hbf, out, l);
        else
            k_bnpool<1><<<dim3(NG, 2), 512, 0, stream>>>(zB, ss, gstart, hbf, out, l);
    }
}

// Round 15
// 361.645 us; speedup vs baseline: 1.4029x; 1.4029x over previous
//
#include <hip/hip_runtime.h>

#define NN 50000
#define NE 800000
#define NG 256
#define DD 256
#define NL 3
#define BN_EPS 1e-5f
#define MPAD 50048   // 782 * 64
#define CAP 96       // per-node edge bucket capacity
#define MB2 782      // MPAD / 64 (m-blocks for fused MLP)
#define NBIN 196     // ceil(NN/256) dst bins
#define BINCAP 4608  // fixed binbuf window per bin (mean 4082, +8 sigma)

typedef short bf16x8 __attribute__((ext_vector_type(8)));
typedef float f32x4 __attribute__((ext_vector_type(4)));
typedef unsigned short ushort8 __attribute__((ext_vector_type(8)));

__device__ __forceinline__ unsigned short f2bf(float f) {
    unsigned int u = __float_as_uint(f);
    u += 0x7FFFu + ((u >> 16) & 1u);
    return (unsigned short)(u >> 16);
}
__device__ __forceinline__ float bf2f(unsigned short s) {
    return __uint_as_float(((unsigned int)s) << 16);
}

// ---------- fused setup: f2bf(x), wconv, zpad, zrow, gbounds, bin_cnt=0 ----------
#define R0 3200000          // f2bf float4 groups (NN*DD/4)
#define R1 393216           // wconv elems (6*65536)
#define R2 12288            // zpad elems ((MPAD-NN)*DD)
#define R3 256              // zrow (sentinel row)
#define R4 256              // gbounds
#define R5 NBIN             // bin_cnt zero
#define RTOT (R0 + R1 + R2 + R3 + R4 + R5)

__global__ void k_setup(const float* __restrict__ x, const float* __restrict__ w1,
                        const float* __restrict__ w2, const int* __restrict__ batch,
                        unsigned short* __restrict__ hbf, unsigned short* __restrict__ wt,
                        unsigned short* __restrict__ zbf, int* __restrict__ gstart,
                        int* __restrict__ bin_cnt) {
    int i = blockIdx.x * blockDim.x + threadIdx.x;
    if (i < R0) {
        float4 v = ((const float4*)x)[i];
        ushort4 o;
        o.x = f2bf(v.x); o.y = f2bf(v.y); o.z = f2bf(v.z); o.w = f2bf(v.w);
        ((ushort4*)hbf)[i] = o;
        return;
    }
    i -= R0;
    if (i < R1) {
        int mat = i >> 16;
        int n = (i >> 8) & 255;
        int k = i & 255;
        const float* src = (mat < 3) ? (w1 + ((size_t)mat << 16)) : (w2 + ((size_t)(mat - 3) << 16));
        wt[i] = f2bf(src[k * 256 + n]);
        return;
    }
    i -= R1;
    if (i < R2) { zbf[NN * DD + i] = 0; return; }
    i -= R2;
    if (i < R3) { hbf[(size_t)NN * DD + i] = 0; return; }
    i -= R3;
    if (i < R4) {
        int g = i;
        int lo = 0, hi = NN;
        while (lo < hi) {
            int mid = (lo + hi) >> 1;
            if (batch[mid] < g) lo = mid + 1; else hi = mid;
        }
        gstart[g] = lo;
        if (g == 0) gstart[NG] = NN;
        return;
    }
    i -= R4;
    if (i < R5) bin_cnt[i] = 0;
}

// ---------- binned CSR build, 2 kernels (fixed per-bin windows) ----------
// phase A: LDS histogram -> global cursor reservation -> packed records into bin window
__global__ __launch_bounds__(256) void k_bin2(const int* __restrict__ ei,
                                              int* __restrict__ bin_cnt,
                                              unsigned int* __restrict__ binbuf) {
    __shared__ int hist[NBIN], base[NBIN], lcur[NBIN];
    int t = threadIdx.x;
    for (int i = t; i < NBIN; i += 256) { hist[i] = 0; lcur[i] = 0; }
    __syncthreads();
    int d[4], s[4];
    #pragma unroll
    for (int j = 0; j < 4; ++j) {
        int e = blockIdx.x * 1024 + j * 256 + t;
        if (e < NE) {
            s[j] = ei[e];
            d[j] = ei[NE + e];
            atomicAdd(&hist[d[j] >> 8], 1);
        } else d[j] = -1;
    }
    __syncthreads();
    for (int i = t; i < NBIN; i += 256)
        base[i] = hist[i] ? atomicAdd(&bin_cnt[i], hist[i]) : 0;
    __syncthreads();
    #pragma unroll
    for (int j = 0; j < 4; ++j) {
        if (d[j] >= 0) {
            int b = d[j] >> 8;
            int o = atomicAdd(&lcur[b], 1);
            binbuf[(size_t)b * BINCAP + base[b] + o] = (unsigned)s[j] | ((unsigned)(d[j] & 255) << 16);
        }
    }
}

// phase B: one block per bin -> elist buckets (writes confined to 49KB window) + deg
__global__ __launch_bounds__(256) void k_bin3(const unsigned int* __restrict__ binbuf,
                                              const int* __restrict__ bin_cnt,
                                              unsigned short* __restrict__ elist,
                                              int* __restrict__ deg) {
    __shared__ int ldeg[256];
    int b = blockIdx.x, t = threadIdx.x;
    ldeg[t] = 0;
    __syncthreads();
    int cnt = bin_cnt[b];
    const unsigned int* bb = binbuf + (size_t)b * BINCAP;
    for (int i = t; i < cnt; i += 256) {
        unsigned v = bb[i];
        int src = v & 0xFFFF;
        int dl = v >> 16;
        int pos = atomicAdd(&ldeg[dl], 1);
        elist[(size_t)(b * 256 + dl) * CAP + pos] = (unsigned short)src;
    }
    __syncthreads();
    int node = b * 256 + t;
    if (node < NN) deg[node] = ldeg[t];
}

// ---------- aggregation (structural floor ~58 us: compulsory per-XCD misses;
// needs full-grid occupancy ~20+ waves/CU — fusing into MLP regressed 2.5x, R14) ----------
__global__ __launch_bounds__(256) void k_agg_bf(const unsigned short* __restrict__ h,
                                                const int* __restrict__ deg,
                                                const unsigned short* __restrict__ elist,
                                                unsigned short* __restrict__ z0) {
    int wave = threadIdx.x >> 6;
    int lane = threadIdx.x & 63;
    int node = blockIdx.x * 4 + wave;
    int chunk = lane & 31;
    int half = lane >> 5;
    const ushort8* h8 = (const ushort8*)h;

    float acc[8];
    if (half == 0) {
        ushort8 own = h8[(size_t)node * 32 + chunk];
        #pragma unroll
        for (int j = 0; j < 8; ++j) acc[j] = bf2f(own[j]);
    } else {
        #pragma unroll
        for (int j = 0; j < 8; ++j) acc[j] = 0.f;
    }

    int n = deg[node];
    const unsigned short* el = elist + (size_t)node * CAP;
    int i = 0;
    for (; i + 8 <= n; i += 8) {
        ushort8 sv = *(const ushort8*)(el + i);
        int i0 = half ? sv[1] : sv[0];
        int i1 = half ? sv[3] : sv[2];
        int i2 = half ? sv[5] : sv[4];
        int i3 = half ? sv[7] : sv[6];
        ushort8 r0 = h8[(size_t)i0 * 32 + chunk];
        ushort8 r1 = h8[(size_t)i1 * 32 + chunk];
        ushort8 r2 = h8[(size_t)i2 * 32 + chunk];
        ushort8 r3 = h8[(size_t)i3 * 32 + chunk];
        #pragma unroll
        for (int j = 0; j < 8; ++j) acc[j] += bf2f(r0[j]);
        #pragma unroll
        for (int j = 0; j < 8; ++j) acc[j] += bf2f(r1[j]);
        #pragma unroll
        for (int j = 0; j < 8; ++j) acc[j] += bf2f(r2[j]);
        #pragma unroll
        for (int j = 0; j < 8; ++j) acc[j] += bf2f(r3[j]);
    }
    for (; i < n; i += 2) {
        int s0 = el[i];
        int s1 = (i + 1 < n) ? (int)el[i + 1] : NN;
        int idx = half ? s1 : s0;
        ushort8 r = h8[(size_t)idx * 32 + chunk];
        #pragma unroll
        for (int j = 0; j < 8; ++j) acc[j] += bf2f(r[j]);
    }

    ushort8 o;
    #pragma unroll
    for (int j = 0; j < 8; ++j) {
        float other = __shfl_xor(acc[j], 32);
        o[j] = f2bf(acc[j] + other);
    }
    if (half == 0) ((ushort8*)z0)[(size_t)node * 32 + chunk] = o;
}

// ---------- fused MLP: relu(relu(z@W1+b1)@W2+b2) -> bf16 z + exact fp32 BN partials ----------
// BM=64, 256 threads (4 waves), LDS 74KB -> 2 blocks/CU.
__global__ __launch_bounds__(256, 2) void k_mlp(const unsigned short* __restrict__ A,
                                                const unsigned short* __restrict__ BT1,
                                                const unsigned short* __restrict__ BT2,
                                                const float* __restrict__ b1,
                                                const float* __restrict__ b2,
                                                unsigned short* __restrict__ Cout,
                                                float* __restrict__ pstat) {
    __shared__ short As[64 * 64];      // z tile k-chunk (8 KB)
    __shared__ short Bs[256 * 64];     // W1T / W2T k-chunk (32 KB, reused)
    __shared__ short H1[64 * 256];     // h1 tile, group-swizzled (32 KB)
    __shared__ float spart[256][2];    // per-col sum/sumsq (2 KB)
    int tid = threadIdx.x;
    int lane = tid & 63;
    int wc = tid >> 6;                 // wave = output col quadrant
    long m0 = (long)blockIdx.x * 64;
    const int r = lane & 15, hi = lane >> 4;

    f32x4 acc[4][4];
    #pragma unroll
    for (int m = 0; m < 4; ++m)
        #pragma unroll
        for (int n = 0; n < 4; ++n)
            acc[m][n] = (f32x4){0.f, 0.f, 0.f, 0.f};

    // ---- GEMM1: h1 = relu(z @ W1 + b1) ----
    for (int k0 = 0; k0 < DD; k0 += 64) {
        #pragma unroll
        for (int p = 0; p < 2; ++p) {
            int flat = p * 256 + tid;
            int row = flat >> 3, c8 = flat & 7;
            int slot = c8 ^ (row & 7);
            *(bf16x8*)(As + row * 64 + slot * 8) =
                *(const bf16x8*)(A + (m0 + row) * DD + k0 + c8 * 8);
        }
        #pragma unroll
        for (int p = 0; p < 8; ++p) {
            int flat = p * 256 + tid;
            int row = flat >> 3, c8 = flat & 7;
            int slot = c8 ^ (row & 7);
            *(bf16x8*)(Bs + row * 64 + slot * 8) =
                *(const bf16x8*)(BT1 + (long)row * DD + k0 + c8 * 8);
        }
        __syncthreads();
        bf16x8 af[4][2], bfr[4][2];
        #pragma unroll
        for (int m = 0; m < 4; ++m) {
            int row = m * 16 + r;
            #pragma unroll
            for (int kk = 0; kk < 2; ++kk) {
                int slot = (kk * 4 + hi) ^ (row & 7);
                af[m][kk] = *(const bf16x8*)(As + row * 64 + slot * 8);
            }
        }
        #pragma unroll
        for (int n = 0; n < 4; ++n) {
            int col = wc * 64 + n * 16 + r;
            #pragma unroll
            for (int kk = 0; kk < 2; ++kk) {
                int slot = (kk * 4 + hi) ^ (col & 7);
                bfr[n][kk] = *(const bf16x8*)(Bs + col * 64 + slot * 8);
            }
        }
        #pragma unroll
        for (int kk = 0; kk < 2; ++kk)
            #pragma unroll
            for (int m = 0; m < 4; ++m)
                #pragma unroll
                for (int n = 0; n < 4; ++n)
                    acc[m][n] = __builtin_amdgcn_mfma_f32_16x16x32_bf16(af[m][kk], bfr[n][kk], acc[m][n], 0, 0, 0);
        __syncthreads();
    }

    // h1 epilogue -> LDS (group-swizzled: group g stored at g^(row&7))
    #pragma unroll
    for (int n = 0; n < 4; ++n) {
        int col = wc * 64 + n * 16 + r;
        float bv = b1[col];
        int g = col >> 3, j8 = col & 7;
        #pragma unroll
        for (int m = 0; m < 4; ++m) {
            #pragma unroll
            for (int j = 0; j < 4; ++j) {
                int row = m * 16 + hi * 4 + j;
                float v = acc[m][n][j] + bv;
                v = v > 0.f ? v : 0.f;
                H1[row * 256 + (g ^ (row & 7)) * 8 + j8] = (short)f2bf(v);
            }
        }
    }
    #pragma unroll
    for (int m = 0; m < 4; ++m)
        #pragma unroll
        for (int n = 0; n < 4; ++n)
            acc[m][n] = (f32x4){0.f, 0.f, 0.f, 0.f};
    __syncthreads();

    // ---- GEMM2: y = relu(h1 @ W2 + b2) ----
    for (int k0 = 0; k0 < DD; k0 += 64) {
        #pragma unroll
        for (int p = 0; p < 8; ++p) {
            int flat = p * 256 + tid;
            int row = flat >> 3, c8 = flat & 7;
            int slot = c8 ^ (row & 7);
            *(bf16x8*)(Bs + row * 64 + slot * 8) =
                *(const bf16x8*)(BT2 + (long)row * DD + k0 + c8 * 8);
        }
        __syncthreads();
        bf16x8 af[4][2], bfr[4][2];
        #pragma unroll
        for (int m = 0; m < 4; ++m) {
            int row = m * 16 + r;
            #pragma unroll
            for (int kk = 0; kk < 2; ++kk) {
                int g = (k0 >> 3) + kk * 4 + hi;
                af[m][kk] = *(const bf16x8*)(H1 + row * 256 + (g ^ (row & 7)) * 8);
            }
        }
        #pragma unroll
        for (int n = 0; n < 4; ++n) {
            int col = wc * 64 + n * 16 + r;
            #pragma unroll
            for (int kk = 0; kk < 2; ++kk) {
                int slot = (kk * 4 + hi) ^ (col & 7);
                bfr[n][kk] = *(const bf16x8*)(Bs + col * 64 + slot * 8);
            }
        }
        #pragma unroll
        for (int kk = 0; kk < 2; ++kk)
            #pragma unroll
            for (int m = 0; m < 4; ++m)
                #pragma unroll
                for (int n = 0; n < 4; ++n)
                    acc[m][n] = __builtin_amdgcn_mfma_f32_16x16x32_bf16(af[m][kk], bfr[n][kk], acc[m][n], 0, 0, 0);
        __syncthreads();
    }

    // epilogue: bias + relu -> bf16 z out; BN partials from EXACT fp32 values
    #pragma unroll
    for (int n = 0; n < 4; ++n) {
        int col = wc * 64 + n * 16 + r;
        float bv = b2[col];
        float cs = 0.f, cs2 = 0.f;
        #pragma unroll
        for (int m = 0; m < 4; ++m) {
            #pragma unroll
            for (int j = 0; j < 4; ++j) {
                long grow = m0 + m * 16 + hi * 4 + j;
                float v = acc[m][n][j] + bv;
                v = v > 0.f ? v : 0.f;
                Cout[grow * DD + col] = f2bf(v);
                float vm = (grow < NN) ? v : 0.f;
                cs += vm; cs2 += vm * vm;
            }
        }
        cs  += __shfl_xor(cs, 16);  cs  += __shfl_xor(cs, 32);
        cs2 += __shfl_xor(cs2, 16); cs2 += __shfl_xor(cs2, 32);
        if (hi == 0) {
            spart[col][0] = cs;
            spart[col][1] = cs2;
        }
    }
    __syncthreads();
    pstat[(size_t)blockIdx.x * 512 + tid] = spart[tid][0];
    pstat[(size_t)blockIdx.x * 512 + 256 + tid] = spart[tid][1];
}

// reduce per-block partials -> BN scale/shift (one block per column, fixed tree)
__global__ __launch_bounds__(256) void k_bnscale2(const float* __restrict__ pstat,
                                                  const float* __restrict__ gamma,
                                                  const float* __restrict__ beta,
                                                  float* __restrict__ ss) {
    int c = blockIdx.x;
    int t = threadIdx.x;
    float s = 0.f, s2 = 0.f;
    for (int mb = t; mb < MB2; mb += 256) {
        s  += pstat[(size_t)mb * 512 + c];
        s2 += pstat[(size_t)mb * 512 + 256 + c];
    }
    __shared__ float rs[256], rs2[256];
    rs[t] = s; rs2[t] = s2;
    __syncthreads();
    #pragma unroll
    for (int d = 128; d > 0; d >>= 1) {
        if (t < d) { rs[t] += rs[t + d]; rs2[t] += rs2[t + d]; }
        __syncthreads();
    }
    if (t == 0) {
        float mean = rs[0] * (1.0f / NN);
        float var = rs2[0] * (1.0f / NN) - mean * mean;
        float sc = gamma[c] * rsqrtf(var + BN_EPS);
        ss[c] = sc;
        ss[DD + c] = beta[c] - mean * sc;
    }
}

// fused BN-apply + bf16 emit + pool over bf16 z; grid (NG, 2): col-half per blockIdx.y.
template<int LAST>
__global__ __launch_bounds__(512) void k_bnpool(const unsigned short* __restrict__ z,
                                                const float* __restrict__ ss,
                                                const int* __restrict__ gstart,
                                                unsigned short* __restrict__ hbf,
                                                float* __restrict__ out, int layer) {
    __shared__ float4 red[16][32];
    int g = blockIdx.x;
    int ch = blockIdx.y;
    int t = threadIdx.x;
    int q = t & 31, rg = t >> 5;
    int cq = ch * 32 + q;
    float4 sc = ((const float4*)ss)[cq];
    float4 sh = ((const float4*)(ss + DD))[cq];
    int lo = gstart[g], hi = gstart[g + 1];
    float4 s = {0.f, 0.f, 0.f, 0.f};
    const ushort4* z4 = (const ushort4*)z;
    ushort4* h4 = (ushort4*)hbf;
    for (int r = lo + rg; r < hi; r += 16) {
        ushort4 zv = z4[(size_t)r * 64 + cq];
        float4 v;
        v.x = bf2f(zv.x) * sc.x + sh.x;
        v.y = bf2f(zv.y) * sc.y + sh.y;
        v.z = bf2f(zv.z) * sc.z + sh.z;
        v.w = bf2f(zv.w) * sc.w + sh.w;
        s.x += v.x; s.y += v.y; s.z += v.z; s.w += v.w;
        if (!LAST) {
            ushort4 o;
            o.x = f2bf(v.x); o.y = f2bf(v.y); o.z = f2bf(v.z); o.w = f2bf(v.w);
            h4[(size_t)r * 64 + cq] = o;
        }
    }
    red[rg][q] = s;
    __syncthreads();
    #pragma unroll
    for (int d = 8; d > 0; d >>= 1) {
        if (rg < d) {
            float4 a = red[rg][q], b = red[rg + d][q];
            a.x += b.x; a.y += b.y; a.z += b.z; a.w += b.w;
            red[rg][q] = a;
        }
        __syncthreads();
    }
    if (rg == 0) {
        ((float4*)(out + (size_t)g * (NL * DD) + layer * DD))[cq] = red[0][q];
    }
}

extern "C" void kernel_launch(void* const* d_in, const int* in_sizes, int n_in,
                              void* d_out, int out_size, void* d_ws, size_t ws_size,
                              hipStream_t stream) {
    const float* x     = (const float*)d_in[0];
    const int*   ei    = (const int*)d_in[1];
    const int*   batch = (const int*)d_in[2];
    const float* w1    = (const float*)d_in[3];
    const float* b1    = (const float*)d_in[4];
    const float* w2    = (const float*)d_in[5];
    const float* b2    = (const float*)d_in[6];
    const float* gamma = (const float*)d_in[7];
    const float* beta  = (const float*)d_in[8];
    float* out = (float*)d_out;

    char* ws = (char*)d_ws;
    size_t off = 0;
    auto alloc = [&](size_t bytes) -> void* {
        void* p = ws + off;
        off += (bytes + 255) & ~size_t(255);
        return p;
    };
    unsigned short* zB   = (unsigned short*)alloc((size_t)MPAD * DD * 2);        // bf16 MLP out
    unsigned short* zbf  = (unsigned short*)alloc((size_t)MPAD * DD * 2);        // agg out (MLP A)
    unsigned short* hbf  = (unsigned short*)alloc((size_t)(NN + 64) * DD * 2);   // h bf16 + sentinel
    unsigned short* wt   = (unsigned short*)alloc((size_t)6 * DD * DD * 2);
    int* deg    = (int*)alloc((size_t)NN * 4);
    unsigned short* elist = (unsigned short*)alloc((size_t)NN * CAP * 2);
    unsigned int* binbuf = (unsigned int*)alloc((size_t)NBIN * BINCAP * 4);
    int* bin_cnt    = (int*)alloc(NBIN * 4);
    int* gstart = (int*)alloc((size_t)(NG + 1) * 4);
    float* pstat = (float*)alloc((size_t)MB2 * 512 * 4);
    float* ss   = (float*)alloc(2 * DD * 4);

    k_setup<<<(RTOT + 255) / 256, 256, 0, stream>>>(x, w1, w2, batch, hbf, wt, zbf, gstart, bin_cnt);
    const int EB = (NE + 1023) / 1024;   // 782
    k_bin2<<<EB, 256, 0, stream>>>(ei, bin_cnt, binbuf);
    k_bin3<<<NBIN, 256, 0, stream>>>(binbuf, bin_cnt, elist, deg);

    for (int l = 0; l < NL; ++l) {
        k_agg_bf<<<NN / 4, 256, 0, stream>>>(hbf, deg, elist, zbf);
        k_mlp<<<MB2, 256, 0, stream>>>(zbf, wt + (size_t)l * DD * DD,
                                       wt + (size_t)(3 + l) * DD * DD,
                                       b1 + l * DD, b2 + l * DD, zB, pstat);
        k_bnscale2<<<DD, 256, 0, stream>>>(pstat, gamma + l * DD, beta + l * DD, ss);
        if (l < NL - 1)
            k_bnpool<0><<<dim3(NG, 2), 512, 0, stream>>>(zB, ss, gstart, hbf, out, l);
        else
            k_bnpool<1><<<dim3(NG, 2), 512, 0, stream>>>(zB, ss, gstart, hbf, out, l);
    }
}